// Round 1
// baseline (205.147 us; speedup 1.0000x reference)
//
#include <hip/hip_runtime.h>
#include <hip/hip_bf16.h>

#define TB 16384
#define CDIM 512
#define OUTD 512
#define NE 16
#define NE_TOT 17
#define LOSS_SCALE 0.01f

typedef __bf16 bf16_t;
typedef bf16_t bf16x8 __attribute__((ext_vector_type(8)));
typedef float f32x4 __attribute__((ext_vector_type(4)));
typedef unsigned short ushort4_t __attribute__((ext_vector_type(4)));
typedef unsigned short ushort8_t __attribute__((ext_vector_type(8)));

__device__ __forceinline__ unsigned short f2bf(float f) {
    unsigned int u = __float_as_uint(f);
    u += 0x7fffu + ((u >> 16) & 1u);   // round-to-nearest-even
    return (unsigned short)(u >> 16);
}

// ---------------- init ----------------
__global__ void k_init_small(int* counts, float* importance) {
    int t = threadIdx.x;
    if (t < NE) { counts[t] = 0; importance[t] = 0.f; }
    if (t == NE) counts[NE] = TB;   // bias "expert" covers all tokens
}

__global__ void k_init_y(float* __restrict__ y, const float* __restrict__ bias_b) {
    int i = blockIdx.x * 256 + threadIdx.x;          // float4 index over TB*OUTD/4
    int c4 = (i & (OUTD / 4 - 1)) * 4;
    float4 v = *(const float4*)(bias_b + c4);
    *(float4*)(y + (long)i * 4) = v;
}

// pw_w1 [16][OUTD*CDIM] fp32 and bias_w [OUTD][CDIM] fp32 -> wbf [17][OUTD][CDIM] bf16
__global__ void k_wconv(const float* __restrict__ pw, const float* __restrict__ bw,
                        unsigned short* __restrict__ wbf) {
    long i = (long)blockIdx.x * 256 + threadIdx.x;   // float4 index
    const long NPW = (long)NE * OUTD * CDIM / 4;
    const long NTOT = (long)NE_TOT * OUTD * CDIM / 4;
    if (i >= NTOT) return;
    const float* src = (i < NPW) ? (pw + i * 4) : (bw + (i - NPW) * 4);
    float4 v = *(const float4*)src;
    ushort4_t o;
    o[0] = f2bf(v.x); o[1] = f2bf(v.y); o[2] = f2bf(v.z); o[3] = f2bf(v.w);
    *(ushort4_t*)(wbf + i * 4) = o;
}

// ---------------- gating ----------------
// 16 tokens per 256-thread block. Computes energies (fp64), top-2 mask, softmax,
// importance partials, expert token lists, and x -> bf16 cache.
__global__ __launch_bounds__(256) void k_gate(
    const float* __restrict__ x, const float* __restrict__ aw, const float* __restrict__ ab,
    unsigned short* __restrict__ xbf, int* __restrict__ counts,
    int* __restrict__ idx_list, float* __restrict__ wgt_list, float* __restrict__ importance)
{
    __shared__ float xs[16][CDIM];
    __shared__ float imp_s[NE];
    __shared__ int cnt_s[NE];
    __shared__ int base_s[NE];
    int tid = threadIdx.x;
    int n0 = blockIdx.x * 16;
    if (tid < NE) { imp_s[tid] = 0.f; cnt_s[tid] = 0; }

    // stage 16 token rows into LDS; emit bf16 cache on the way
    #pragma unroll
    for (int i = 0; i < 8; ++i) {
        int f = tid + i * 256;            // 0..2047 float4s
        int t = f >> 7;
        int c4 = (f & 127) << 2;
        float4 v = *(const float4*)(x + (long)(n0 + t) * CDIM + c4);
        xs[t][c4 + 0] = v.x; xs[t][c4 + 1] = v.y;
        xs[t][c4 + 2] = v.z; xs[t][c4 + 3] = v.w;
        ushort4_t b;
        b[0] = f2bf(v.x); b[1] = f2bf(v.y); b[2] = f2bf(v.z); b[3] = f2bf(v.w);
        *(ushort4_t*)(xbf + (long)(n0 + t) * CDIM + c4) = b;
    }
    __syncthreads();

    int tok = tid >> 4, e = tid & 15;
    int n = n0 + tok;
    const float* wrow = aw + e * CDIM;
    double acc = 0.0;
    for (int c = 0; c < CDIM; c += 4) {
        float4 xv = *(const float4*)(&xs[tok][c]);
        float4 wv = *(const float4*)(wrow + c);
        acc += (double)xv.x * wv.x + (double)xv.y * wv.y
             + (double)xv.z * wv.z + (double)xv.w * wv.w;
    }
    double v = acc + (double)ab[e];

    // (max, 2nd max) over the 16-lane group
    double m1 = v, m2 = -1.0e300;
    #pragma unroll
    for (int off = 8; off >= 1; off >>= 1) {
        double o1 = __shfl_xor(m1, off, 64);
        double o2 = __shfl_xor(m2, off, 64);
        double hi = fmax(m1, o1), lo = fmin(m1, o1);
        m1 = hi;
        m2 = fmax(lo, fmax(m2, o2));
    }
    double p = (v >= m2) ? exp(v - m1) : 0.0;
    double z = p;
    #pragma unroll
    for (int off = 8; off >= 1; off >>= 1) z += __shfl_xor(z, off, 64);
    float resp = (float)(p / z);

    atomicAdd(&imp_s[e], resp);
    int ls = -1;
    if (resp > 0.f) ls = atomicAdd(&cnt_s[e], 1);
    __syncthreads();
    if (tid < NE) {
        base_s[tid] = atomicAdd(&counts[tid], cnt_s[tid]);
        unsafeAtomicAdd(&importance[tid], imp_s[tid]);
    }
    __syncthreads();
    if (ls >= 0) {
        int g = base_s[e] + ls;
        idx_list[e * TB + g] = n;
        wgt_list[e * TB + g] = resp;
    }
    if (e == 0) {  // bias expert: identity list, weight 1
        idx_list[NE * TB + n] = n;
        wgt_list[NE * TB + n] = 1.0f;
    }
}

__global__ void k_loss(const float* __restrict__ importance, float* __restrict__ out_loss) {
    int l = threadIdx.x;
    float v = (l < NE) ? importance[l] : 0.f;
    float s = v;
    #pragma unroll
    for (int off = 8; off >= 1; off >>= 1) s += __shfl_xor(s, off, 64);
    float mean = s / 16.f;
    float d = (l < NE) ? (v - mean) : 0.f;
    float ss = d * d;
    #pragma unroll
    for (int off = 8; off >= 1; off >>= 1) ss += __shfl_xor(ss, off, 64);
    if (l == 0) {
        float stdv = sqrtf(ss / 15.f);   // ddof=1
        out_loss[0] = LOSS_SCALE * stdv / mean;
    }
}

// ---------------- grouped GEMM ----------------
#define BM 128
#define BN 128
#define BK 32
#define LDK 40   // padded LDS stride (shorts): 80 B rows -> only 2-way bank aliasing

__global__ __launch_bounds__(256) void k_moe_gemm(
    const unsigned short* __restrict__ xbf, const unsigned short* __restrict__ wbf,
    const int* __restrict__ counts, const int* __restrict__ idx_list,
    const float* __restrict__ wgt_list, float* __restrict__ y)
{
    int e = blockIdx.z;
    int cnt = counts[e];
    int m0 = blockIdx.y * BM;
    if (m0 >= cnt) return;
    int n0 = blockIdx.x * BN;
    int tid = threadIdx.x;

    __shared__ unsigned short As[BM][LDK];
    __shared__ unsigned short Bs[BN][LDK];

    const int* my_idx = idx_list + e * TB;
    const float* my_wgt = wgt_list + e * TB;

    int ar0 = tid >> 2;             // staging row 0..63
    int ac = (tid & 3) * 8;         // staging col (elements)
    int r0 = m0 + ar0, r1 = r0 + 64;
    int tok0 = (r0 < cnt) ? my_idx[r0] : 0;
    int tok1 = (r1 < cnt) ? my_idx[r1] : 0;
    const unsigned short* ap0 = xbf + (long)tok0 * CDIM + ac;
    const unsigned short* ap1 = xbf + (long)tok1 * CDIM + ac;
    const unsigned short* bp0 = wbf + (long)e * OUTD * CDIM + (long)(n0 + ar0) * CDIM + ac;
    const unsigned short* bp1 = bp0 + 64 * CDIM;

    int wave = tid >> 6, lane = tid & 63;
    int wm = wave >> 1, wn = wave & 1;
    int fr = lane & 15, fq = lane >> 4;

    f32x4 acc[4][4];
    #pragma unroll
    for (int m = 0; m < 4; ++m)
        #pragma unroll
        for (int nn = 0; nn < 4; ++nn) acc[m][nn] = (f32x4){0.f, 0.f, 0.f, 0.f};

    for (int k0 = 0; k0 < CDIM; k0 += BK) {
        ushort8_t va0 = *(const ushort8_t*)(ap0 + k0);
        ushort8_t va1 = *(const ushort8_t*)(ap1 + k0);
        ushort8_t vb0 = *(const ushort8_t*)(bp0 + k0);
        ushort8_t vb1 = *(const ushort8_t*)(bp1 + k0);
        __syncthreads();
        *(ushort8_t*)(&As[ar0][ac]) = va0;
        *(ushort8_t*)(&As[ar0 + 64][ac]) = va1;
        *(ushort8_t*)(&Bs[ar0][ac]) = vb0;
        *(ushort8_t*)(&Bs[ar0 + 64][ac]) = vb1;
        __syncthreads();
        bf16x8 af[4], bfr[4];
        #pragma unroll
        for (int m = 0; m < 4; ++m)
            af[m] = *(const bf16x8*)(&As[wm * 64 + m * 16 + fr][fq * 8]);
        #pragma unroll
        for (int nn = 0; nn < 4; ++nn)
            bfr[nn] = *(const bf16x8*)(&Bs[wn * 64 + nn * 16 + fr][fq * 8]);
        #pragma unroll
        for (int m = 0; m < 4; ++m)
            #pragma unroll
            for (int nn = 0; nn < 4; ++nn)
                acc[m][nn] = __builtin_amdgcn_mfma_f32_16x16x32_bf16(af[m], bfr[nn], acc[m][nn], 0, 0, 0);
    }

    // epilogue: weighted atomic scatter into y
    #pragma unroll
    for (int m = 0; m < 4; ++m) {
        #pragma unroll
        for (int q = 0; q < 4; ++q) {
            int r = m0 + wm * 64 + m * 16 + fq * 4 + q;
            if (r < cnt) {
                int t = my_idx[r];
                float w = my_wgt[r];
                float* yrow = y + (long)t * OUTD + n0 + wn * 64 + fr;
                #pragma unroll
                for (int nn = 0; nn < 4; ++nn)
                    unsafeAtomicAdd(yrow + nn * 16, w * acc[m][nn][q]);
            }
        }
    }
}

extern "C" void kernel_launch(void* const* d_in, const int* in_sizes, int n_in,
                              void* d_out, int out_size, void* d_ws, size_t ws_size,
                              hipStream_t stream) {
    const float* x        = (const float*)d_in[0];
    const float* assign_w = (const float*)d_in[1];
    const float* assign_b = (const float*)d_in[2];
    const float* pw_w1    = (const float*)d_in[3];
    const float* bias_w   = (const float*)d_in[4];
    const float* bias_b   = (const float*)d_in[5];
    float* y    = (float*)d_out;                 // [TB*OUTD]
    float* loss = y + (size_t)TB * OUTD;         // [1]

    char* ws = (char*)d_ws;
    unsigned short* xbf  = (unsigned short*)(ws);                 // 16,777,216 B
    unsigned short* wbf  = (unsigned short*)(ws + 16777216);      //  8,912,896 B
    int*   idx_list      = (int*)  (ws + 25690112);               //  1,114,112 B
    float* wgt_list      = (float*)(ws + 26804224);               //  1,114,112 B
    int*   counts        = (int*)  (ws + 27918336);
    float* importance    = (float*)(ws + 27918592);

    k_init_small<<<1, 64, 0, stream>>>(counts, importance);
    k_init_y<<<TB * OUTD / 4 / 256, 256, 0, stream>>>(y, bias_b);
    k_wconv<<<(NE_TOT * OUTD * CDIM / 4 + 255) / 256, 256, 0, stream>>>(pw_w1, bias_w, wbf);
    k_gate<<<TB / 16, 256, 0, stream>>>(x, assign_w, assign_b, xbf, counts,
                                        idx_list, wgt_list, importance);
    k_loss<<<1, 64, 0, stream>>>(importance, loss);
    dim3 g(OUTD / BN, TB / BM, NE_TOT);
    k_moe_gemm<<<g, 256, 0, stream>>>(xbf, wbf, counts, idx_list, wgt_list, y);
}

// Round 2
// 183.741 us; speedup vs baseline: 1.1165x; 1.1165x over previous
//
#include <hip/hip_runtime.h>
#include <hip/hip_bf16.h>

#define TB 16384
#define CDIM 512
#define OUTD 512
#define NE 16
#define NE_TOT 17
#define LOSS_SCALE 0.01f
#define BM 128
#define BN 128
#define BK 64
#define MAX_SCHED 320

typedef __bf16 bf16_t;
typedef bf16_t bf16x8 __attribute__((ext_vector_type(8)));
typedef float f32x4 __attribute__((ext_vector_type(4)));
typedef unsigned short ushort4_t __attribute__((ext_vector_type(4)));

__device__ __forceinline__ unsigned short f2bf(float f) {
    unsigned int u = __float_as_uint(f);
    u += 0x7fffu + ((u >> 16) & 1u);   // round-to-nearest-even
    return (unsigned short)(u >> 16);
}

__device__ __forceinline__ void async_copy16(void* lds, const void* g) {
    __builtin_amdgcn_global_load_lds(
        (const __attribute__((address_space(1))) unsigned int*)g,
        (__attribute__((address_space(3))) unsigned int*)lds, 16, 0, 0);
}

// ---------------- init ----------------
__global__ void k_init_small(int* counts, float* importance, int* wflag) {
    int t = threadIdx.x;
    if (t < NE) { counts[t] = 0; importance[t] = 0.f; }
    if (t == 0) *wflag = 0;
}

// pw_w1 [16][OUT*C] fp32 and bias_w [OUT][C] fp32 -> wbf [17][OUT][C] bf16
__global__ void k_wconv(const float* __restrict__ pw, const float* __restrict__ bw,
                        unsigned short* __restrict__ wbf) {
    long i = (long)blockIdx.x * 256 + threadIdx.x;   // float4 index
    const long NPW = (long)NE * OUTD * CDIM / 4;
    const long NTOT = (long)NE_TOT * OUTD * CDIM / 4;
    if (i >= NTOT) return;
    const float* src = (i < NPW) ? (pw + i * 4) : (bw + (i - NPW) * 4);
    float4 v = *(const float4*)src;
    ushort4_t o;
    o[0] = f2bf(v.x); o[1] = f2bf(v.y); o[2] = f2bf(v.z); o[3] = f2bf(v.w);
    *(ushort4_t*)(wbf + i * 4) = o;
}

__global__ void k_wzero(const float* __restrict__ bw, int* __restrict__ wflag) {
    int i = blockIdx.x * 256 + threadIdx.x;          // float4 idx over 512*512/4
    float4 v = *(const float4*)(bw + (long)i * 4);
    if (v.x != 0.f || v.y != 0.f || v.z != 0.f || v.w != 0.f) atomicOr(wflag, 1);
}

// ---------------- gating ----------------
__global__ __launch_bounds__(256) void k_gate(
    const float* __restrict__ x, const float* __restrict__ aw, const float* __restrict__ ab,
    unsigned short* __restrict__ xbf, int* __restrict__ counts,
    int* __restrict__ idx_list, float* __restrict__ wgt_list, float* __restrict__ importance)
{
    __shared__ float xs[16][CDIM];
    __shared__ float imp_s[NE];
    __shared__ int cnt_s[NE];
    __shared__ int base_s[NE];
    int tid = threadIdx.x;
    int n0 = blockIdx.x * 16;
    if (tid < NE) { imp_s[tid] = 0.f; cnt_s[tid] = 0; }

    #pragma unroll
    for (int i = 0; i < 8; ++i) {
        int f = tid + i * 256;
        int t = f >> 7;
        int c4 = (f & 127) << 2;
        float4 v = *(const float4*)(x + (long)(n0 + t) * CDIM + c4);
        xs[t][c4 + 0] = v.x; xs[t][c4 + 1] = v.y;
        xs[t][c4 + 2] = v.z; xs[t][c4 + 3] = v.w;
        ushort4_t b;
        b[0] = f2bf(v.x); b[1] = f2bf(v.y); b[2] = f2bf(v.z); b[3] = f2bf(v.w);
        *(ushort4_t*)(xbf + (long)(n0 + t) * CDIM + c4) = b;
    }
    __syncthreads();

    int tok = tid >> 4, e = tid & 15;
    int n = n0 + tok;
    const float* wrow = aw + e * CDIM;
    double acc = 0.0;                       // fp64 dot: exact top-2 ordering vs np ref
    for (int c = 0; c < CDIM; c += 4) {
        float4 xv = *(const float4*)(&xs[tok][c]);
        float4 wv = *(const float4*)(wrow + c);
        acc += (double)xv.x * wv.x + (double)xv.y * wv.y
             + (double)xv.z * wv.z + (double)xv.w * wv.w;
    }
    double v = acc + (double)ab[e];

    double m1 = v, m2 = -1.0e300;           // (max, 2nd max) over 16-lane group
    #pragma unroll
    for (int off = 8; off >= 1; off >>= 1) {
        double o1 = __shfl_xor(m1, off, 64);
        double o2 = __shfl_xor(m2, off, 64);
        double hi = fmax(m1, o1), lo = fmin(m1, o1);
        m1 = hi;
        m2 = fmax(lo, fmax(m2, o2));
    }
    float p = (v >= m2) ? expf((float)(v - m1)) : 0.f;
    float z = p;
    #pragma unroll
    for (int off = 8; off >= 1; off >>= 1) z += __shfl_xor(z, off, 64);
    float resp = p / z;

    atomicAdd(&imp_s[e], resp);
    int ls = -1;
    if (resp > 0.f) ls = atomicAdd(&cnt_s[e], 1);
    __syncthreads();
    if (tid < NE) {
        base_s[tid] = atomicAdd(&counts[tid], cnt_s[tid]);
        unsafeAtomicAdd(&importance[tid], imp_s[tid]);
    }
    __syncthreads();
    if (ls >= 0) {
        int g = base_s[e] + ls;
        idx_list[e * TB + g] = n;
        wgt_list[e * TB + g] = resp;
    }
}

__global__ void k_loss(const float* __restrict__ importance, float* __restrict__ out_loss) {
    int l = threadIdx.x;
    float v = (l < NE) ? importance[l] : 0.f;
    float s = v;
    #pragma unroll
    for (int off = 8; off >= 1; off >>= 1) s += __shfl_xor(s, off, 64);
    float mean = s / 16.f;
    float d = (l < NE) ? (v - mean) : 0.f;
    float ss = d * d;
    #pragma unroll
    for (int off = 8; off >= 1; off >>= 1) ss += __shfl_xor(ss, off, 64);
    if (l == 0) {
        float stdv = sqrtf(ss / 15.f);   // ddof=1
        out_loss[0] = LOSS_SCALE * stdv / mean;
    }
}

// ---------------- schedule compaction ----------------
__global__ void k_sched(const int* __restrict__ counts, int* __restrict__ sched,
                        int* __restrict__ sched_n) {
    __shared__ int base_s[NE];
    int t = threadIdx.x;
    if (t == 0) {
        int p = 0;
        for (int e = 0; e < NE; ++e) { base_s[e] = p; p += (counts[e] + BM - 1) / BM; }
        *sched_n = p;
    }
    __syncthreads();
    if (t < NE) {
        int nb = (counts[t] + BM - 1) / BM;
        int b = base_s[t];
        for (int i = 0; i < nb; ++i) sched[b + i] = (t << 16) | i;
    }
}

// ---------------- GEMM (m97 structure: gload_lds + XOR swizzle, BK=64) ----------------
template<bool DENSE>
__global__ __launch_bounds__(256) void k_gemm(
    const unsigned short* __restrict__ xbf, const unsigned short* __restrict__ wbf,
    const int* __restrict__ counts, const int* __restrict__ idx_list,
    const float* __restrict__ wgt_list, const int* __restrict__ sched,
    const int* __restrict__ sched_n, const int* __restrict__ wflag,
    const float* __restrict__ bias_b, float* __restrict__ y)
{
    int e, m0, cnt;
    if (DENSE) {
        e = NE; m0 = blockIdx.y * BM; cnt = TB;
    } else {
        if ((int)blockIdx.y >= *sched_n) return;
        int s = sched[blockIdx.y];
        e = s >> 16; m0 = (s & 0xffff) * BM; cnt = counts[e];
    }
    int n0 = blockIdx.x * BN;
    int tid = threadIdx.x;
    int wave = tid >> 6, lane = tid & 63;
    int wm = wave >> 1, wn = wave & 1;
    int fr = lane & 15, fq = lane >> 4;

    __shared__ unsigned short As[BM * BK];   // 16 KiB, linear rows of 128 B
    __shared__ unsigned short Bs[BN * BK];   // 16 KiB

    const int* my_idx = idx_list + e * TB;
    const float* my_wgt = wgt_list + e * TB;

    f32x4 acc[4][4];
    #pragma unroll
    for (int m = 0; m < 4; ++m)
        #pragma unroll
        for (int n = 0; n < 4; ++n) acc[m][n] = (f32x4){0.f, 0.f, 0.f, 0.f};

    bool do_mm = DENSE ? (*wflag != 0) : true;

    if (do_mm) {
        // staging: per wave, 4 calls each for A and B; lane l covers
        // row = c*32 + wave*8 + (l>>3), 16B chunk (l&7). Source is pre-swizzled
        // (chunk ^ row&7) so linear gload_lds dest + swizzled ds_read match (rule #21).
        int srow = wave * 8 + (lane >> 3);
        int cg = lane & 7;
        const unsigned short* aSrc[4];
        const unsigned short* bSrc[4];
        #pragma unroll
        for (int c = 0; c < 4; ++c) {
            int row = c * 32 + srow;
            int sc = (cg ^ (row & 7)) * 8;
            int tok;
            if (DENSE) tok = m0 + row;
            else { int rr = m0 + row; if (rr >= cnt) rr = cnt - 1; tok = my_idx[rr]; }
            aSrc[c] = xbf + (size_t)tok * CDIM + sc;
            bSrc[c] = wbf + ((size_t)e * OUTD + n0 + row) * CDIM + sc;
        }
        for (int k0 = 0; k0 < CDIM; k0 += BK) {
            __syncthreads();                       // prev tile fully consumed
            #pragma unroll
            for (int c = 0; c < 4; ++c) {
                async_copy16(&As[(c * 32 + wave * 8) * BK], aSrc[c] + k0);
                async_copy16(&Bs[(c * 32 + wave * 8) * BK], bSrc[c] + k0);
            }
            __syncthreads();                       // compiler drains vmcnt(0) here
            #pragma unroll
            for (int s = 0; s < 2; ++s) {
                bf16x8 af[4], bv[4];
                #pragma unroll
                for (int m = 0; m < 4; ++m) {
                    int row = wm * 64 + m * 16 + fr;
                    int ch = ((s * 4 + fq) ^ (row & 7)) * 8;
                    af[m] = *(const bf16x8*)(&As[row * BK + ch]);
                }
                #pragma unroll
                for (int n = 0; n < 4; ++n) {
                    int row = wn * 64 + n * 16 + fr;
                    int ch = ((s * 4 + fq) ^ (row & 7)) * 8;
                    bv[n] = *(const bf16x8*)(&Bs[row * BK + ch]);
                }
                #pragma unroll
                for (int m = 0; m < 4; ++m)
                    #pragma unroll
                    for (int n = 0; n < 4; ++n)
                        acc[m][n] = __builtin_amdgcn_mfma_f32_16x16x32_bf16(af[m], bv[n], acc[m][n], 0, 0, 0);
            }
        }
    }

    if (DENSE) {
        float bb[4];
        #pragma unroll
        for (int n = 0; n < 4; ++n) bb[n] = bias_b[n0 + wn * 64 + n * 16 + fr];
        #pragma unroll
        for (int m = 0; m < 4; ++m)
            #pragma unroll
            for (int q = 0; q < 4; ++q) {
                int r = m0 + wm * 64 + m * 16 + fq * 4 + q;
                float* yrow = y + (size_t)r * OUTD + n0 + wn * 64 + fr;
                #pragma unroll
                for (int n = 0; n < 4; ++n) yrow[n * 16] = acc[m][n][q] + bb[n];
            }
    } else {
        #pragma unroll
        for (int m = 0; m < 4; ++m)
            #pragma unroll
            for (int q = 0; q < 4; ++q) {
                int r = m0 + wm * 64 + m * 16 + fq * 4 + q;
                if (r < cnt) {
                    int t = my_idx[r];
                    float w = my_wgt[r];
                    float* yrow = y + (size_t)t * OUTD + n0 + wn * 64 + fr;
                    #pragma unroll
                    for (int n = 0; n < 4; ++n)
                        unsafeAtomicAdd(yrow + n * 16, w * acc[m][n][q]);
                }
            }
    }
}

extern "C" void kernel_launch(void* const* d_in, const int* in_sizes, int n_in,
                              void* d_out, int out_size, void* d_ws, size_t ws_size,
                              hipStream_t stream) {
    const float* x        = (const float*)d_in[0];
    const float* assign_w = (const float*)d_in[1];
    const float* assign_b = (const float*)d_in[2];
    const float* pw_w1    = (const float*)d_in[3];
    const float* bias_w   = (const float*)d_in[4];
    const float* bias_b   = (const float*)d_in[5];
    float* y    = (float*)d_out;                 // [TB*OUTD]
    float* loss = y + (size_t)TB * OUTD;         // [1]

    char* ws = (char*)d_ws;
    unsigned short* xbf  = (unsigned short*)(ws);                 // 16,777,216 B
    unsigned short* wbf  = (unsigned short*)(ws + 16777216);      //  8,912,896 B
    int*   idx_list      = (int*)  (ws + 25690112);               //  1,048,576 B
    float* wgt_list      = (float*)(ws + 26738688);               //  1,048,576 B
    int*   counts        = (int*)  (ws + 27787264);
    float* importance    = (float*)(ws + 27787328);
    int*   sched         = (int*)  (ws + 27787392);               //  1,280 B
    int*   sched_n       = (int*)  (ws + 27788672);
    int*   wflag         = (int*)  (ws + 27788676);

    k_init_small<<<1, 64, 0, stream>>>(counts, importance, wflag);
    k_wconv<<<(NE_TOT * OUTD * CDIM / 4 + 255) / 256, 256, 0, stream>>>(pw_w1, bias_w, wbf);
    k_wzero<<<OUTD * CDIM / 4 / 256, 256, 0, stream>>>(bias_w, wflag);
    k_gate<<<TB / 16, 256, 0, stream>>>(x, assign_w, assign_b, xbf, counts,
                                        idx_list, wgt_list, importance);
    k_sched<<<1, 64, 0, stream>>>(counts, sched, sched_n);
    k_loss<<<1, 64, 0, stream>>>(importance, loss);
    // dense bias GEMM first (plain stores), then expert GEMM (atomic adds) — stream-ordered
    k_gemm<true ><<<dim3(OUTD / BN, TB / BM), 256, 0, stream>>>(
        xbf, wbf, counts, idx_list, wgt_list, sched, sched_n, wflag, bias_b, y);
    k_gemm<false><<<dim3(OUTD / BN, MAX_SCHED), 256, 0, stream>>>(
        xbf, wbf, counts, idx_list, wgt_list, sched, sched_n, wflag, bias_b, y);
}

// Round 3
// 181.070 us; speedup vs baseline: 1.1330x; 1.0147x over previous
//
#include <hip/hip_runtime.h>
#include <hip/hip_bf16.h>

#define TB 16384
#define CDIM 512
#define OUTD 512
#define NE 16
#define NE_TOT 17
#define LOSS_SCALE 0.01f
#define BM 128
#define BN 128
#define BK 64
#define MAX_SCHED 144
#define MAXFLAG 8192
#define MARGIN 1e-3f

typedef __bf16 bf16_t;
typedef bf16_t bf16x8 __attribute__((ext_vector_type(8)));
typedef float f32x4 __attribute__((ext_vector_type(4)));
typedef unsigned short ushort4_t __attribute__((ext_vector_type(4)));

__device__ __forceinline__ unsigned short f2bf(float f) {
    unsigned int u = __float_as_uint(f);
    u += 0x7fffu + ((u >> 16) & 1u);   // round-to-nearest-even
    return (unsigned short)(u >> 16);
}

__device__ __forceinline__ void async_copy16(void* lds, const void* g) {
    __builtin_amdgcn_global_load_lds(
        (const __attribute__((address_space(1))) unsigned int*)g,
        (__attribute__((address_space(3))) unsigned int*)lds, 16, 0, 0);
}

// ---------------- init ----------------
__global__ void k_init_small(int* cnt0, int* cnt1, float* importance, int* nflag, int* wflag) {
    int t = threadIdx.x;
    if (t < NE) { cnt0[t] = 0; cnt1[t] = 0; importance[t] = 0.f; }
    if (t == 0) { *nflag = 0; *wflag = 0; }
}

// pw_w1 [16][OUT*C] fp32 and bias_w [OUT][C] fp32 -> wbf [17][OUT][C] bf16
__global__ void k_wconv(const float* __restrict__ pw, const float* __restrict__ bw,
                        unsigned short* __restrict__ wbf) {
    long i = (long)blockIdx.x * 256 + threadIdx.x;   // float4 index
    const long NPW = (long)NE * OUTD * CDIM / 4;
    const long NTOT = (long)NE_TOT * OUTD * CDIM / 4;
    if (i >= NTOT) return;
    const float* src = (i < NPW) ? (pw + i * 4) : (bw + (i - NPW) * 4);
    float4 v = *(const float4*)src;
    ushort4_t o;
    o[0] = f2bf(v.x); o[1] = f2bf(v.y); o[2] = f2bf(v.z); o[3] = f2bf(v.w);
    *(ushort4_t*)(wbf + i * 4) = o;
}

__global__ void k_wzero(const float* __restrict__ bw, int* __restrict__ wflag) {
    int i = blockIdx.x * 256 + threadIdx.x;
    float4 v = *(const float4*)(bw + (long)i * 4);
    if (v.x != 0.f || v.y != 0.f || v.z != 0.f || v.w != 0.f) atomicOr(wflag, 1);
}

// ---------------- gating (fp32 + flag) ----------------
// 16 tokens/block, 256 threads: thread (tok, e) computes one fp32 energy.
__global__ __launch_bounds__(256) void k_gate(
    const float* __restrict__ x, const float* __restrict__ aw, const float* __restrict__ ab,
    unsigned short* __restrict__ xbf, int* __restrict__ dec, float2* __restrict__ respd,
    int* __restrict__ flaglist, int* __restrict__ nflag, float* __restrict__ importance)
{
    __shared__ float4 xs[16][128];   // XOR-swizzled chunks (col = cc ^ (t&3)), 32 KiB
    __shared__ float imp_s[NE];
    int tid = threadIdx.x;
    int n0 = blockIdx.x * 16;
    if (tid < NE) imp_s[tid] = 0.f;

    #pragma unroll
    for (int i = 0; i < 8; ++i) {
        int f = tid + i * 256;           // chunk id 0..2047
        int t = f >> 7, cc = f & 127;
        float4 v = *(const float4*)(x + (size_t)(n0 + t) * CDIM + cc * 4);
        xs[t][cc ^ (t & 3)] = v;
        ushort4_t b;
        b[0] = f2bf(v.x); b[1] = f2bf(v.y); b[2] = f2bf(v.z); b[3] = f2bf(v.w);
        *(ushort4_t*)(xbf + (size_t)(n0 + t) * CDIM + cc * 4) = b;
    }
    __syncthreads();

    int tok = tid >> 4, e = tid & 15;
    int n = n0 + tok;
    const float4* wrow = (const float4*)(aw + e * CDIM);
    float4 a4 = {0.f, 0.f, 0.f, 0.f};
    #pragma unroll 8
    for (int cc = 0; cc < 128; ++cc) {
        float4 xv = xs[tok][cc ^ (tok & 3)];
        float4 wv = wrow[cc];
        a4.x = fmaf(xv.x, wv.x, a4.x);
        a4.y = fmaf(xv.y, wv.y, a4.y);
        a4.z = fmaf(xv.z, wv.z, a4.z);
        a4.w = fmaf(xv.w, wv.w, a4.w);
    }
    float energy = ((a4.x + a4.y) + (a4.z + a4.w)) + ab[e];

    // top-3 over the 16-lane expert group (sorted-triple butterfly merge)
    float m1 = energy, m2 = -3.4e38f, m3 = -3.4e38f;
    #pragma unroll
    for (int off = 1; off <= 8; off <<= 1) {
        float o1 = __shfl_xor(m1, off, 64);
        float o2 = __shfl_xor(m2, off, 64);
        float o3 = __shfl_xor(m3, off, 64);
        float M1 = fmaxf(m1, o1);
        float x1 = fminf(m1, o1);
        float h2 = fmaxf(m2, o2), l2 = fminf(m2, o2);
        float M2 = fmaxf(x1, h2);
        float x2 = fminf(x1, h2);
        float M3 = fmaxf(fmaxf(x2, l2), fmaxf(m3, o3));
        m1 = M1; m2 = M2; m3 = M3;
    }
    float p = (energy >= m2) ? expf(energy - m1) : 0.f;
    float z = p;
    #pragma unroll
    for (int off = 1; off <= 8; off <<= 1) z += __shfl_xor(z, off, 64);
    float resp = p / z;

    unsigned long long mask = __ballot(p > 0.f);
    int l = tid & 63;
    unsigned int mymask = (unsigned int)((mask >> ((l >> 4) * 16)) & 0xffffULL);
    int e_lo = __builtin_ctz(mymask);
    int e_hi = 31 - __builtin_clz(mymask);
    float r_lo = __shfl(resp, (l & ~15) + e_lo, 64);
    float r_hi = __shfl(resp, (l & ~15) + e_hi, 64);
    bool flg = (m2 - m3) < MARGIN;
    if (e == 0) {
        dec[n] = e_lo | (e_hi << 8);
        respd[n] = make_float2(r_lo, r_hi);
        if (flg) {
            int ix = atomicAdd(nflag, 1);
            if (ix < MAXFLAG) flaglist[ix] = n;
        }
    }
    atomicAdd(&imp_s[e], resp);
    __syncthreads();
    if (tid < NE) unsafeAtomicAdd(&importance[tid], imp_s[tid]);
}

// ---------------- fp64 repair for ambiguous tokens ----------------
__global__ __launch_bounds__(256) void k_repair(
    const float* __restrict__ x, const float* __restrict__ aw, const float* __restrict__ ab,
    const int* __restrict__ flaglist, const int* __restrict__ nflag,
    int* __restrict__ dec, float2* __restrict__ respd, float* __restrict__ importance)
{
    __shared__ double part[16][17];
    __shared__ double Ed[16];
    int tid = threadIdx.x;
    int e = tid >> 4, p = tid & 15;
    int nf = *nflag; if (nf > MAXFLAG) nf = MAXFLAG;
    for (int fi = blockIdx.x; fi < nf; fi += gridDim.x) {
        int n = flaglist[fi];
        const float* xp = x + (size_t)n * CDIM + p * 32;
        const float* wp = aw + e * CDIM + p * 32;
        double acc = 0.0;
        for (int j = 0; j < 32; ++j) acc = fma((double)xp[j], (double)wp[j], acc);
        part[e][p] = acc;
        __syncthreads();
        if (tid < 16) {
            double s = (double)ab[tid];
            for (int q = 0; q < 16; ++q) s += part[tid][q];
            Ed[tid] = s;
        }
        __syncthreads();
        if (tid == 0) {
            double m1 = -1e300, m2 = -1e300, m3 = -1e300;
            for (int q = 0; q < 16; ++q) {
                double v = Ed[q];
                if (v > m1) { m3 = m2; m2 = m1; m1 = v; }
                else if (v > m2) { m3 = m2; m2 = v; }
                else if (v > m3) { m3 = v; }
            }
            int elo = -1, ehi = -1;
            for (int q = 0; q < 16; ++q)
                if (Ed[q] >= m2) { if (elo < 0) elo = q; else ehi = q; }
            double plo = exp(Ed[elo] - m1), phi = exp(Ed[ehi] - m1);
            double zz = plo + phi;
            float rlo = (float)(plo / zz), rhi = (float)(phi / zz);
            int od = dec[n]; float2 orr = respd[n];
            unsafeAtomicAdd(&importance[od & 0xff], -orr.x);
            unsafeAtomicAdd(&importance[(od >> 8) & 0xff], -orr.y);
            unsafeAtomicAdd(&importance[elo], rlo);
            unsafeAtomicAdd(&importance[ehi], rhi);
            dec[n] = elo | (ehi << 8);
            respd[n] = make_float2(rlo, rhi);
        }
        __syncthreads();
    }
}

__global__ void k_loss(const float* __restrict__ importance, float* __restrict__ out_loss) {
    int l = threadIdx.x;
    float v = (l < NE) ? importance[l] : 0.f;
    float s = v;
    #pragma unroll
    for (int off = 8; off >= 1; off >>= 1) s += __shfl_xor(s, off, 64);
    float mean = s / 16.f;
    float d = (l < NE) ? (v - mean) : 0.f;
    float ss = d * d;
    #pragma unroll
    for (int off = 8; off >= 1; off >>= 1) ss += __shfl_xor(ss, off, 64);
    if (l == 0) {
        float stdv = sqrtf(ss / 15.f);   // ddof=1
        out_loss[0] = LOSS_SCALE * stdv / mean;
    }
}

// ---------------- rank-list building ----------------
__global__ __launch_bounds__(256) void k_build(
    const int* __restrict__ dec, int* __restrict__ cnt0, int* __restrict__ cnt1,
    int* __restrict__ idx0, int* __restrict__ idx1)
{
    __shared__ int l0[NE], l1[NE], b0[NE], b1[NE];
    int tid = threadIdx.x;
    if (tid < NE) { l0[tid] = 0; l1[tid] = 0; }
    __syncthreads();
    int n = blockIdx.x * 256 + tid;
    int d = dec[n];
    int elo = d & 0xff, ehi = (d >> 8) & 0xff;
    int p0 = atomicAdd(&l0[elo], 1);
    int p1 = atomicAdd(&l1[ehi], 1);
    __syncthreads();
    if (tid < NE) {
        b0[tid] = atomicAdd(&cnt0[tid], l0[tid]);
        b1[tid] = atomicAdd(&cnt1[tid], l1[tid]);
    }
    __syncthreads();
    idx0[elo * TB + b0[elo] + p0] = n;
    idx1[ehi * TB + b1[ehi] + p1] = n;
}

__global__ void k_sched(const int* __restrict__ cnt0, const int* __restrict__ cnt1,
                        int* __restrict__ sched0, int* __restrict__ sched1,
                        int* __restrict__ sn0, int* __restrict__ sn1) {
    int t = threadIdx.x;
    if (t == 0) {
        int p = 0;
        for (int e = 0; e < NE; ++e) {
            int nb = (cnt0[e] + BM - 1) / BM;
            for (int i = 0; i < nb; ++i) sched0[p++] = (e << 16) | i;
        }
        *sn0 = p;
    }
    if (t == 1) {
        int p = 0;
        for (int e = 0; e < NE; ++e) {
            int nb = (cnt1[e] + BM - 1) / BM;
            for (int i = 0; i < nb; ++i) sched1[p++] = (e << 16) | i;
        }
        *sn1 = p;
    }
}

// ---------------- rank GEMMs (m97 structure; plain stores, no atomics) ----------------
template<int RANK>
__global__ __launch_bounds__(256) void k_gemm(
    const unsigned short* __restrict__ xbf, const unsigned short* __restrict__ wbf,
    const int* __restrict__ cnts, const int* __restrict__ idx,
    const float2* __restrict__ respd, const int* __restrict__ sched,
    const int* __restrict__ sn, const float* __restrict__ bias_b, float* __restrict__ y)
{
    if ((int)blockIdx.y >= *sn) return;
    int s = sched[blockIdx.y];
    int e = s >> 16, m0 = (s & 0xffff) * BM, cnt = cnts[e];
    int n0 = blockIdx.x * BN;
    int tid = threadIdx.x;
    int wave = tid >> 6, lane = tid & 63;
    int wm = wave >> 1, wn = wave & 1;
    int fr = lane & 15, fq = lane >> 4;

    __shared__ unsigned short As[BM * BK];   // 16 KiB
    __shared__ unsigned short Bs[BN * BK];   // 16 KiB

    const int* my_idx = idx + e * TB;

    f32x4 acc[4][4];
    #pragma unroll
    for (int m = 0; m < 4; ++m)
        #pragma unroll
        for (int nn = 0; nn < 4; ++nn) acc[m][nn] = (f32x4){0.f, 0.f, 0.f, 0.f};

    // staging: row = c*32 + wave*8 + (l>>3), 16B chunk (l&7); source pre-swizzled
    // (chunk ^ row&7) so linear gload_lds dest + swizzled ds_read match (rule #21).
    int srow = wave * 8 + (lane >> 3);
    int cg = lane & 7;
    const unsigned short* aSrc[4];
    const unsigned short* bSrc[4];
    #pragma unroll
    for (int c = 0; c < 4; ++c) {
        int row = c * 32 + srow;
        int sc = (cg ^ (row & 7)) * 8;
        int rr = m0 + row; if (rr >= cnt) rr = cnt - 1;
        int tok = my_idx[rr];
        aSrc[c] = xbf + (size_t)tok * CDIM + sc;
        bSrc[c] = wbf + ((size_t)e * OUTD + n0 + row) * CDIM + sc;
    }
    for (int k0 = 0; k0 < CDIM; k0 += BK) {
        __syncthreads();
        #pragma unroll
        for (int c = 0; c < 4; ++c) {
            async_copy16(&As[(c * 32 + wave * 8) * BK], aSrc[c] + k0);
            async_copy16(&Bs[(c * 32 + wave * 8) * BK], bSrc[c] + k0);
        }
        __syncthreads();
        #pragma unroll
        for (int ss = 0; ss < 2; ++ss) {
            bf16x8 af[4], bv[4];
            #pragma unroll
            for (int m = 0; m < 4; ++m) {
                int row = wm * 64 + m * 16 + fr;
                int ch = ((ss * 4 + fq) ^ (row & 7)) * 8;
                af[m] = *(const bf16x8*)(&As[row * BK + ch]);
            }
            #pragma unroll
            for (int nn = 0; nn < 4; ++nn) {
                int row = wn * 64 + nn * 16 + fr;
                int ch = ((ss * 4 + fq) ^ (row & 7)) * 8;
                bv[nn] = *(const bf16x8*)(&Bs[row * BK + ch]);
            }
            #pragma unroll
            for (int m = 0; m < 4; ++m)
                #pragma unroll
                for (int nn = 0; nn < 4; ++nn)
                    acc[m][nn] = __builtin_amdgcn_mfma_f32_16x16x32_bf16(af[m], bv[nn], acc[m][nn], 0, 0, 0);
        }
    }

    float bb[4];
    if (RANK == 0) {
        #pragma unroll
        for (int nn = 0; nn < 4; ++nn) bb[nn] = bias_b[n0 + wn * 64 + nn * 16 + fr];
    }
    #pragma unroll
    for (int m = 0; m < 4; ++m)
        #pragma unroll
        for (int q = 0; q < 4; ++q) {
            int r = m0 + wm * 64 + m * 16 + fq * 4 + q;
            if (r < cnt) {
                int tok = my_idx[r];
                float2 rp = respd[tok];
                float w = (RANK == 0) ? rp.x : rp.y;
                float* yrow = y + (size_t)tok * OUTD + n0 + wn * 64 + fr;
                #pragma unroll
                for (int nn = 0; nn < 4; ++nn) {
                    if (RANK == 0) yrow[nn * 16] = fmaf(w, acc[m][nn][q], bb[nn]);
                    else           yrow[nn * 16] += w * acc[m][nn][q];
                }
            }
        }
}

// dense bias GEMM (only when bias_w != 0): y += x @ bias_w^T  (slot 16 of wbf)
__global__ __launch_bounds__(256) void k_dense(
    const unsigned short* __restrict__ xbf, const unsigned short* __restrict__ wbf,
    const int* __restrict__ wflag, float* __restrict__ y)
{
    if (*wflag == 0) return;
    int e = NE;
    int m0 = blockIdx.y * BM;
    int n0 = blockIdx.x * BN;
    int tid = threadIdx.x;
    int wave = tid >> 6, lane = tid & 63;
    int wm = wave >> 1, wn = wave & 1;
    int fr = lane & 15, fq = lane >> 4;

    __shared__ unsigned short As[BM * BK];
    __shared__ unsigned short Bs[BN * BK];

    f32x4 acc[4][4];
    #pragma unroll
    for (int m = 0; m < 4; ++m)
        #pragma unroll
        for (int nn = 0; nn < 4; ++nn) acc[m][nn] = (f32x4){0.f, 0.f, 0.f, 0.f};

    int srow = wave * 8 + (lane >> 3);
    int cg = lane & 7;
    const unsigned short* aSrc[4];
    const unsigned short* bSrc[4];
    #pragma unroll
    for (int c = 0; c < 4; ++c) {
        int row = c * 32 + srow;
        int sc = (cg ^ (row & 7)) * 8;
        aSrc[c] = xbf + (size_t)(m0 + row) * CDIM + sc;
        bSrc[c] = wbf + ((size_t)e * OUTD + n0 + row) * CDIM + sc;
    }
    for (int k0 = 0; k0 < CDIM; k0 += BK) {
        __syncthreads();
        #pragma unroll
        for (int c = 0; c < 4; ++c) {
            async_copy16(&As[(c * 32 + wave * 8) * BK], aSrc[c] + k0);
            async_copy16(&Bs[(c * 32 + wave * 8) * BK], bSrc[c] + k0);
        }
        __syncthreads();
        #pragma unroll
        for (int ss = 0; ss < 2; ++ss) {
            bf16x8 af[4], bv[4];
            #pragma unroll
            for (int m = 0; m < 4; ++m) {
                int row = wm * 64 + m * 16 + fr;
                int ch = ((ss * 4 + fq) ^ (row & 7)) * 8;
                af[m] = *(const bf16x8*)(&As[row * BK + ch]);
            }
            #pragma unroll
            for (int nn = 0; nn < 4; ++nn) {
                int row = wn * 64 + nn * 16 + fr;
                int ch = ((ss * 4 + fq) ^ (row & 7)) * 8;
                bv[nn] = *(const bf16x8*)(&Bs[row * BK + ch]);
            }
            #pragma unroll
            for (int m = 0; m < 4; ++m)
                #pragma unroll
                for (int nn = 0; nn < 4; ++nn)
                    acc[m][nn] = __builtin_amdgcn_mfma_f32_16x16x32_bf16(af[m], bv[nn], acc[m][nn], 0, 0, 0);
        }
    }
    #pragma unroll
    for (int m = 0; m < 4; ++m)
        #pragma unroll
        for (int q = 0; q < 4; ++q) {
            int r = m0 + wm * 64 + m * 16 + fq * 4 + q;
            float* yrow = y + (size_t)r * OUTD + n0 + wn * 64 + fr;
            #pragma unroll
            for (int nn = 0; nn < 4; ++nn) yrow[nn * 16] += acc[m][nn][q];
        }
}

extern "C" void kernel_launch(void* const* d_in, const int* in_sizes, int n_in,
                              void* d_out, int out_size, void* d_ws, size_t ws_size,
                              hipStream_t stream) {
    const float* x        = (const float*)d_in[0];
    const float* assign_w = (const float*)d_in[1];
    const float* assign_b = (const float*)d_in[2];
    const float* pw_w1    = (const float*)d_in[3];
    const float* bias_w   = (const float*)d_in[4];
    const float* bias_b   = (const float*)d_in[5];
    float* y    = (float*)d_out;                 // [TB*OUTD]
    float* loss = y + (size_t)TB * OUTD;         // [1]

    char* ws = (char*)d_ws;
    unsigned short* xbf = (unsigned short*)(ws);                  // 16,777,216 B
    unsigned short* wbf = (unsigned short*)(ws + 16777216);       //  8,912,896 B
    int*    idx0      = (int*)   (ws + 25690112);                 //  1,048,576 B
    int*    idx1      = (int*)   (ws + 26738688);                 //  1,048,576 B
    int*    dec       = (int*)   (ws + 27787264);                 //     65,536 B
    float2* respd     = (float2*)(ws + 27852800);                 //    131,072 B
    int*    flaglist  = (int*)   (ws + 27983872);                 //     32,768 B
    char*   misc      = ws + 28016640;
    int*    cnt0      = (int*)   (misc + 0);
    int*    cnt1      = (int*)   (misc + 64);
    float*  importance= (float*) (misc + 128);
    int*    nflag     = (int*)   (misc + 192);
    int*    wflag     = (int*)   (misc + 196);
    int*    sn0       = (int*)   (misc + 200);
    int*    sn1       = (int*)   (misc + 204);
    int*    sched0    = (int*)   (misc + 256);
    int*    sched1    = (int*)   (misc + 896);

    k_init_small<<<1, 64, 0, stream>>>(cnt0, cnt1, importance, nflag, wflag);
    k_wconv<<<(NE_TOT * OUTD * CDIM / 4 + 255) / 256, 256, 0, stream>>>(pw_w1, bias_w, wbf);
    k_wzero<<<OUTD * CDIM / 4 / 256, 256, 0, stream>>>(bias_w, wflag);
    k_gate<<<TB / 16, 256, 0, stream>>>(x, assign_w, assign_b, xbf, dec, respd,
                                        flaglist, nflag, importance);
    k_repair<<<32, 256, 0, stream>>>(x, assign_w, assign_b, flaglist, nflag,
                                     dec, respd, importance);
    k_loss<<<1, 64, 0, stream>>>(importance, loss);
    k_build<<<TB / 256, 256, 0, stream>>>(dec, cnt0, cnt1, idx0, idx1);
    k_sched<<<1, 64, 0, stream>>>(cnt0, cnt1, sched0, sched1, sn0, sn1);
    k_gemm<0><<<dim3(OUTD / BN, MAX_SCHED), 256, 0, stream>>>(
        xbf, wbf, cnt0, idx0, respd, sched0, sn0, bias_b, y);
    k_gemm<1><<<dim3(OUTD / BN, MAX_SCHED), 256, 0, stream>>>(
        xbf, wbf, cnt1, idx1, respd, sched1, sn1, bias_b, y);
    k_dense<<<dim3(OUTD / BN, TB / BM), 256, 0, stream>>>(xbf, wbf, wflag, y);
}

// Round 4
// 130.567 us; speedup vs baseline: 1.5712x; 1.3868x over previous
//
#include <hip/hip_runtime.h>
#include <hip/hip_bf16.h>

#define TB 16384
#define CDIM 512
#define OUTD 512
#define NE 16
#define NE_TOT 17
#define LOSS_SCALE 0.01f
#define BM 128
#define BN 128
#define BK 64
#define MAX_SCHED 144
#define MAXFLAG 8192
#define MARGIN 1e-3f

typedef __bf16 bf16_t;
typedef bf16_t bf16x8 __attribute__((ext_vector_type(8)));
typedef float f32x4 __attribute__((ext_vector_type(4)));
typedef unsigned short ushort4_t __attribute__((ext_vector_type(4)));
typedef unsigned short ushort8_t __attribute__((ext_vector_type(8)));

__device__ __forceinline__ unsigned short f2bf(float f) {
    unsigned int u = __float_as_uint(f);
    u += 0x7fffu + ((u >> 16) & 1u);   // round-to-nearest-even
    return (unsigned short)(u >> 16);
}
__device__ __forceinline__ float bf2f(unsigned short h) {
    return __uint_as_float((unsigned int)h << 16);
}

__device__ __forceinline__ void async_copy16(void* lds, const void* g) {
    __builtin_amdgcn_global_load_lds(
        (const __attribute__((address_space(1))) unsigned int*)g,
        (__attribute__((address_space(3))) unsigned int*)lds, 16, 0, 0);
}

// ---------------- prep: init small state + assign_w hi/lo bf16 split ----------------
__global__ __launch_bounds__(256) void k_prep(
    const float* __restrict__ aw, unsigned short* __restrict__ awhl,
    int* cnt0, int* cnt1, float* importance, int* nflag, int* wflag)
{
    int t = threadIdx.x;
    if (t < NE) { cnt0[t] = 0; cnt1[t] = 0; importance[t] = 0.f; }
    if (t == 0) { *nflag = 0; *wflag = 0; }
    for (int i = t; i < NE * CDIM; i += 256) {
        float f = aw[i];
        unsigned short h = f2bf(f);
        float r = f - bf2f(h);
        awhl[i] = h;
        awhl[NE * CDIM + i] = f2bf(r);
    }
}

// pw_w1 + bias_w -> wbf [17][OUT][C] bf16; also detect bias_w != 0
__global__ void k_wconv(const float* __restrict__ pw, const float* __restrict__ bw,
                        unsigned short* __restrict__ wbf, int* __restrict__ wflag) {
    long i = (long)blockIdx.x * 256 + threadIdx.x;   // float4 index
    const long NPW = (long)NE * OUTD * CDIM / 4;
    const long NTOT = (long)NE_TOT * OUTD * CDIM / 4;
    if (i >= NTOT) return;
    const float* src = (i < NPW) ? (pw + i * 4) : (bw + (i - NPW) * 4);
    float4 v = *(const float4*)src;
    ushort4_t o;
    o[0] = f2bf(v.x); o[1] = f2bf(v.y); o[2] = f2bf(v.z); o[3] = f2bf(v.w);
    *(ushort4_t*)(wbf + i * 4) = o;
    if (i >= NPW && (v.x != 0.f || v.y != 0.f || v.z != 0.f || v.w != 0.f))
        atomicOr(wflag, 1);
}

// ---------------- gating via MFMA hi/lo ----------------
// 4 waves/block, each wave one 16-token x 16-expert tile.
// A-frag load mapping: token=l&15, k=(l>>4)*8+j ; D mapping: token=(l>>4)*4+q, expert=l&15.
__global__ __launch_bounds__(256) void k_gate(
    const float* __restrict__ x, const unsigned short* __restrict__ awhl,
    const float* __restrict__ ab, unsigned short* __restrict__ xbf,
    int* __restrict__ dec, float2* __restrict__ respd,
    int* __restrict__ flaglist, int* __restrict__ nflag, float* __restrict__ importance)
{
    __shared__ float imp_s[NE];
    int tid = threadIdx.x;
    if (tid < NE) imp_s[tid] = 0.f;
    __syncthreads();

    int wv = tid >> 6, l = tid & 63;
    int n0 = blockIdx.x * 64 + wv * 16;
    int e = l & 15;          // expert (B-frag row / D col); also A-load token row
    int kg = l >> 4;         // k-group

    const float* xrow = x + (size_t)(n0 + e) * CDIM + kg * 8;
    unsigned short* xbrow = xbf + (size_t)(n0 + e) * CDIM + kg * 8;
    const unsigned short* whiP = awhl + e * CDIM + kg * 8;
    const unsigned short* wloP = whiP + NE * CDIM;

    f32x4 acc = (f32x4){0.f, 0.f, 0.f, 0.f};
    #pragma unroll 4
    for (int ks = 0; ks < 16; ++ks) {
        float4 v0 = *(const float4*)(xrow + ks * 32);
        float4 v1 = *(const float4*)(xrow + ks * 32 + 4);
        ushort8_t hx, lx;
        #define CVT(idx, f) { unsigned short h_ = f2bf(f); hx[idx] = h_; \
                              float r_ = (f) - bf2f(h_); lx[idx] = f2bf(r_); }
        CVT(0, v0.x) CVT(1, v0.y) CVT(2, v0.z) CVT(3, v0.w)
        CVT(4, v1.x) CVT(5, v1.y) CVT(6, v1.z) CVT(7, v1.w)
        #undef CVT
        *(ushort8_t*)(xbrow + ks * 32) = hx;
        ushort8_t wh8 = *(const ushort8_t*)(whiP + ks * 32);
        ushort8_t wl8 = *(const ushort8_t*)(wloP + ks * 32);
        bf16x8 ah = *(bf16x8*)&hx, al = *(bf16x8*)&lx;
        bf16x8 bh = *(bf16x8*)&wh8, bl = *(bf16x8*)&wl8;
        acc = __builtin_amdgcn_mfma_f32_16x16x32_bf16(al, bh, acc, 0, 0, 0);
        acc = __builtin_amdgcn_mfma_f32_16x16x32_bf16(ah, bl, acc, 0, 0, 0);
        acc = __builtin_amdgcn_mfma_f32_16x16x32_bf16(ah, bh, acc, 0, 0, 0);
    }
    float bias = ab[e];
    f32x4 E;
    #pragma unroll
    for (int q = 0; q < 4; ++q) E[q] = acc[q] + bias;

    // top-3 butterfly over the 16-lane expert groups, per component
    f32x4 m1 = E, m2, m3;
    #pragma unroll
    for (int q = 0; q < 4; ++q) { m2[q] = -3.4e38f; m3[q] = -3.4e38f; }
    #pragma unroll
    for (int off = 1; off <= 8; off <<= 1) {
        #pragma unroll
        for (int q = 0; q < 4; ++q) {
            float o1 = __shfl_xor(m1[q], off, 64);
            float o2 = __shfl_xor(m2[q], off, 64);
            float o3 = __shfl_xor(m3[q], off, 64);
            float M1 = fmaxf(m1[q], o1), x1 = fminf(m1[q], o1);
            float h2 = fmaxf(m2[q], o2), l2 = fminf(m2[q], o2);
            float M2 = fmaxf(x1, h2), x2 = fminf(x1, h2);
            float M3 = fmaxf(fmaxf(x2, l2), fmaxf(m3[q], o3));
            m1[q] = M1; m2[q] = M2; m3[q] = M3;
        }
    }
    f32x4 p, z;
    #pragma unroll
    for (int q = 0; q < 4; ++q) p[q] = (E[q] >= m2[q]) ? expf(E[q] - m1[q]) : 0.f;
    z = p;
    #pragma unroll
    for (int off = 1; off <= 8; off <<= 1)
        #pragma unroll
        for (int q = 0; q < 4; ++q) z[q] += __shfl_xor(z[q], off, 64);
    f32x4 resp;
    #pragma unroll
    for (int q = 0; q < 4; ++q) resp[q] = p[q] / z[q];

    int grp = l >> 4;
    int elo_q[4], ehi_q[4];
    float rlo_q[4], rhi_q[4];
    #pragma unroll
    for (int q = 0; q < 4; ++q) {
        unsigned long long mq = __ballot(p[q] > 0.f);
        unsigned int sub = (unsigned int)((mq >> (grp * 16)) & 0xffffULL);
        elo_q[q] = __builtin_ctz(sub);
        ehi_q[q] = 31 - __builtin_clz(sub);
        rlo_q[q] = __shfl(resp[q], grp * 16 + elo_q[q], 64);
        rhi_q[q] = __shfl(resp[q], grp * 16 + ehi_q[q], 64);
    }
    if ((l & 15) == 0) {
        #pragma unroll
        for (int q = 0; q < 4; ++q) {
            int n = n0 + grp * 4 + q;
            dec[n] = elo_q[q] | (ehi_q[q] << 8);
            respd[n] = make_float2(rlo_q[q], rhi_q[q]);
            if (m2[q] - m3[q] < MARGIN) {
                int ix = atomicAdd(nflag, 1);
                if (ix < MAXFLAG) flaglist[ix] = n;
            }
        }
    }
    // importance: per-lane sum over its 4 tokens, reduce across the 4 grp copies
    float s = resp[0] + resp[1] + resp[2] + resp[3];
    s += __shfl_xor(s, 16, 64);
    s += __shfl_xor(s, 32, 64);
    if (l < 16) atomicAdd(&imp_s[e], s);
    __syncthreads();
    if (tid < NE) unsafeAtomicAdd(&importance[tid], imp_s[tid]);
}

// ---------------- fp64 repair for ambiguous tokens ----------------
__global__ __launch_bounds__(256) void k_repair(
    const float* __restrict__ x, const float* __restrict__ aw, const float* __restrict__ ab,
    const int* __restrict__ flaglist, const int* __restrict__ nflag,
    int* __restrict__ dec, float2* __restrict__ respd, float* __restrict__ importance)
{
    __shared__ double part[16][17];
    __shared__ double Ed[16];
    int tid = threadIdx.x;
    int e = tid >> 4, p = tid & 15;
    int nf = *nflag; if (nf > MAXFLAG) nf = MAXFLAG;
    for (int fi = blockIdx.x; fi < nf; fi += gridDim.x) {
        int n = flaglist[fi];
        const float* xp = x + (size_t)n * CDIM + p * 32;
        const float* wp = aw + e * CDIM + p * 32;
        double acc = 0.0;
        for (int j = 0; j < 32; ++j) acc = fma((double)xp[j], (double)wp[j], acc);
        part[e][p] = acc;
        __syncthreads();
        if (tid < 16) {
            double s = (double)ab[tid];
            for (int q = 0; q < 16; ++q) s += part[tid][q];
            Ed[tid] = s;
        }
        __syncthreads();
        if (tid == 0) {
            double m1 = -1e300, m2 = -1e300, m3 = -1e300;
            for (int q = 0; q < 16; ++q) {
                double v = Ed[q];
                if (v > m1) { m3 = m2; m2 = m1; m1 = v; }
                else if (v > m2) { m3 = m2; m2 = v; }
                else if (v > m3) { m3 = v; }
            }
            int elo = -1, ehi = -1;
            for (int q = 0; q < 16; ++q)
                if (Ed[q] >= m2) { if (elo < 0) elo = q; else ehi = q; }
            double plo = exp(Ed[elo] - m1), phi = exp(Ed[ehi] - m1);
            double zz = plo + phi;
            float rlo = (float)(plo / zz), rhi = (float)(phi / zz);
            int od = dec[n]; float2 orr = respd[n];
            unsafeAtomicAdd(&importance[od & 0xff], -orr.x);
            unsafeAtomicAdd(&importance[(od >> 8) & 0xff], -orr.y);
            unsafeAtomicAdd(&importance[elo], rlo);
            unsafeAtomicAdd(&importance[ehi], rhi);
            dec[n] = elo | (ehi << 8);
            respd[n] = make_float2(rlo, rhi);
        }
        __syncthreads();
    }
}

// ---------------- rank-list building ----------------
__global__ __launch_bounds__(256) void k_build(
    const int* __restrict__ dec, int* __restrict__ cnt0, int* __restrict__ cnt1,
    int* __restrict__ idx0, int* __restrict__ idx1)
{
    __shared__ int l0[NE], l1[NE], b0[NE], b1[NE];
    int tid = threadIdx.x;
    if (tid < NE) { l0[tid] = 0; l1[tid] = 0; }
    __syncthreads();
    int n = blockIdx.x * 256 + tid;
    int d = dec[n];
    int elo = d & 0xff, ehi = (d >> 8) & 0xff;
    int p0 = atomicAdd(&l0[elo], 1);
    int p1 = atomicAdd(&l1[ehi], 1);
    __syncthreads();
    if (tid < NE) {
        b0[tid] = atomicAdd(&cnt0[tid], l0[tid]);
        b1[tid] = atomicAdd(&cnt1[tid], l1[tid]);
    }
    __syncthreads();
    idx0[elo * TB + b0[elo] + p0] = n;
    idx1[ehi * TB + b1[ehi] + p1] = n;
}

// ---------------- loss + schedule (fused tail) ----------------
__global__ void k_finish(const float* __restrict__ importance, float* __restrict__ out_loss,
                         const int* __restrict__ cnt0, const int* __restrict__ cnt1,
                         int* __restrict__ sched0, int* __restrict__ sched1,
                         int* __restrict__ sn0, int* __restrict__ sn1) {
    int l = threadIdx.x;
    if (l < 64) {
        float v = (l < NE) ? importance[l] : 0.f;
        float s = v;
        #pragma unroll
        for (int off = 8; off >= 1; off >>= 1) s += __shfl_xor(s, off, 64);
        float mean = s / 16.f;
        float d = (l < NE) ? (v - mean) : 0.f;
        float ss = d * d;
        #pragma unroll
        for (int off = 8; off >= 1; off >>= 1) ss += __shfl_xor(ss, off, 64);
        if (l == 0) {
            float stdv = sqrtf(ss / 15.f);   // ddof=1
            out_loss[0] = LOSS_SCALE * stdv / mean;
        }
    } else if (l == 64) {
        int p = 0;
        for (int e = 0; e < NE; ++e) {
            int nb = (cnt0[e] + BM - 1) / BM;
            for (int i = 0; i < nb; ++i) sched0[p++] = (e << 16) | i;
        }
        *sn0 = p;
    } else if (l == 65) {
        int p = 0;
        for (int e = 0; e < NE; ++e) {
            int nb = (cnt1[e] + BM - 1) / BM;
            for (int i = 0; i < nb; ++i) sched1[p++] = (e << 16) | i;
        }
        *sn1 = p;
    }
}

// ---------------- rank GEMMs (m97 structure; plain stores, no atomics) ----------------
template<int RANK>
__global__ __launch_bounds__(256) void k_gemm(
    const unsigned short* __restrict__ xbf, const unsigned short* __restrict__ wbf,
    const int* __restrict__ cnts, const int* __restrict__ idx,
    const float2* __restrict__ respd, const int* __restrict__ sched,
    const int* __restrict__ sn, const float* __restrict__ bias_b, float* __restrict__ y)
{
    if ((int)blockIdx.y >= *sn) return;
    int s = sched[blockIdx.y];
    int e = s >> 16, m0 = (s & 0xffff) * BM, cnt = cnts[e];
    int n0 = blockIdx.x * BN;
    int tid = threadIdx.x;
    int wave = tid >> 6, lane = tid & 63;
    int wm = wave >> 1, wn = wave & 1;
    int fr = lane & 15, fq = lane >> 4;

    __shared__ unsigned short As[BM * BK];   // 16 KiB
    __shared__ unsigned short Bs[BN * BK];   // 16 KiB

    const int* my_idx = idx + e * TB;

    f32x4 acc[4][4];
    #pragma unroll
    for (int m = 0; m < 4; ++m)
        #pragma unroll
        for (int nn = 0; nn < 4; ++nn) acc[m][nn] = (f32x4){0.f, 0.f, 0.f, 0.f};

    int srow = wave * 8 + (lane >> 3);
    int cg = lane & 7;
    const unsigned short* aSrc[4];
    const unsigned short* bSrc[4];
    #pragma unroll
    for (int c = 0; c < 4; ++c) {
        int row = c * 32 + srow;
        int sc = (cg ^ (row & 7)) * 8;
        int rr = m0 + row; if (rr >= cnt) rr = cnt - 1;
        int tok = my_idx[rr];
        aSrc[c] = xbf + (size_t)tok * CDIM + sc;
        bSrc[c] = wbf + ((size_t)e * OUTD + n0 + row) * CDIM + sc;
    }
    for (int k0 = 0; k0 < CDIM; k0 += BK) {
        __syncthreads();
        #pragma unroll
        for (int c = 0; c < 4; ++c) {
            async_copy16(&As[(c * 32 + wave * 8) * BK], aSrc[c] + k0);
            async_copy16(&Bs[(c * 32 + wave * 8) * BK], bSrc[c] + k0);
        }
        __syncthreads();
        #pragma unroll
        for (int ss = 0; ss < 2; ++ss) {
            bf16x8 af[4], bv[4];
            #pragma unroll
            for (int m = 0; m < 4; ++m) {
                int row = wm * 64 + m * 16 + fr;
                int ch = ((ss * 4 + fq) ^ (row & 7)) * 8;
                af[m] = *(const bf16x8*)(&As[row * BK + ch]);
            }
            #pragma unroll
            for (int nn = 0; nn < 4; ++nn) {
                int row = wn * 64 + nn * 16 + fr;
                int ch = ((ss * 4 + fq) ^ (row & 7)) * 8;
                bv[nn] = *(const bf16x8*)(&Bs[row * BK + ch]);
            }
            #pragma unroll
            for (int m = 0; m < 4; ++m)
                #pragma unroll
                for (int nn = 0; nn < 4; ++nn)
                    acc[m][nn] = __builtin_amdgcn_mfma_f32_16x16x32_bf16(af[m], bv[nn], acc[m][nn], 0, 0, 0);
        }
    }

    float bb[4];
    if (RANK == 0) {
        #pragma unroll
        for (int nn = 0; nn < 4; ++nn) bb[nn] = bias_b[n0 + wn * 64 + nn * 16 + fr];
    }
    #pragma unroll
    for (int m = 0; m < 4; ++m)
        #pragma unroll
        for (int q = 0; q < 4; ++q) {
            int r = m0 + wm * 64 + m * 16 + fq * 4 + q;
            if (r < cnt) {
                int tok = my_idx[r];
                float2 rp = respd[tok];
                float w = (RANK == 0) ? rp.x : rp.y;
                float* yrow = y + (size_t)tok * OUTD + n0 + wn * 64 + fr;
                #pragma unroll
                for (int nn = 0; nn < 4; ++nn) {
                    if (RANK == 0) yrow[nn * 16] = fmaf(w, acc[m][nn][q], bb[nn]);
                    else           yrow[nn * 16] += w * acc[m][nn][q];
                }
            }
        }
}

// dense bias GEMM (only when bias_w != 0): y += x @ bias_w^T  (slot 16 of wbf)
__global__ __launch_bounds__(256) void k_dense(
    const unsigned short* __restrict__ xbf, const unsigned short* __restrict__ wbf,
    const int* __restrict__ wflag, float* __restrict__ y)
{
    if (*wflag == 0) return;
    int e = NE;
    int m0 = blockIdx.y * BM;
    int n0 = blockIdx.x * BN;
    int tid = threadIdx.x;
    int wave = tid >> 6, lane = tid & 63;
    int wm = wave >> 1, wn = wave & 1;
    int fr = lane & 15, fq = lane >> 4;

    __shared__ unsigned short As[BM * BK];
    __shared__ unsigned short Bs[BN * BK];

    f32x4 acc[4][4];
    #pragma unroll
    for (int m = 0; m < 4; ++m)
        #pragma unroll
        for (int nn = 0; nn < 4; ++nn) acc[m][nn] = (f32x4){0.f, 0.f, 0.f, 0.f};

    int srow = wave * 8 + (lane >> 3);
    int cg = lane & 7;
    const unsigned short* aSrc[4];
    const unsigned short* bSrc[4];
    #pragma unroll
    for (int c = 0; c < 4; ++c) {
        int row = c * 32 + srow;
        int sc = (cg ^ (row & 7)) * 8;
        aSrc[c] = xbf + (size_t)(m0 + row) * CDIM + sc;
        bSrc[c] = wbf + ((size_t)e * OUTD + n0 + row) * CDIM + sc;
    }
    for (int k0 = 0; k0 < CDIM; k0 += BK) {
        __syncthreads();
        #pragma unroll
        for (int c = 0; c < 4; ++c) {
            async_copy16(&As[(c * 32 + wave * 8) * BK], aSrc[c] + k0);
            async_copy16(&Bs[(c * 32 + wave * 8) * BK], bSrc[c] + k0);
        }
        __syncthreads();
        #pragma unroll
        for (int ss = 0; ss < 2; ++ss) {
            bf16x8 af[4], bv[4];
            #pragma unroll
            for (int m = 0; m < 4; ++m) {
                int row = wm * 64 + m * 16 + fr;
                int ch = ((ss * 4 + fq) ^ (row & 7)) * 8;
                af[m] = *(const bf16x8*)(&As[row * BK + ch]);
            }
            #pragma unroll
            for (int nn = 0; nn < 4; ++nn) {
                int row = wn * 64 + nn * 16 + fr;
                int ch = ((ss * 4 + fq) ^ (row & 7)) * 8;
                bv[nn] = *(const bf16x8*)(&Bs[row * BK + ch]);
            }
            #pragma unroll
            for (int m = 0; m < 4; ++m)
                #pragma unroll
                for (int nn = 0; nn < 4; ++nn)
                    acc[m][nn] = __builtin_amdgcn_mfma_f32_16x16x32_bf16(af[m], bv[nn], acc[m][nn], 0, 0, 0);
        }
    }
    #pragma unroll
    for (int m = 0; m < 4; ++m)
        #pragma unroll
        for (int q = 0; q < 4; ++q) {
            int r = m0 + wm * 64 + m * 16 + fq * 4 + q;
            float* yrow = y + (size_t)r * OUTD + n0 + wn * 64 + fr;
            #pragma unroll
            for (int nn = 0; nn < 4; ++nn) yrow[nn * 16] += acc[m][nn][q];
        }
}

extern "C" void kernel_launch(void* const* d_in, const int* in_sizes, int n_in,
                              void* d_out, int out_size, void* d_ws, size_t ws_size,
                              hipStream_t stream) {
    const float* x        = (const float*)d_in[0];
    const float* assign_w = (const float*)d_in[1];
    const float* assign_b = (const float*)d_in[2];
    const float* pw_w1    = (const float*)d_in[3];
    const float* bias_w   = (const float*)d_in[4];
    const float* bias_b   = (const float*)d_in[5];
    float* y    = (float*)d_out;                 // [TB*OUTD]
    float* loss = y + (size_t)TB * OUTD;         // [1]

    char* ws = (char*)d_ws;
    unsigned short* xbf  = (unsigned short*)(ws);                 // 16,777,216 B
    unsigned short* wbf  = (unsigned short*)(ws + 16777216);      //  8,912,896 B
    int*    idx0      = (int*)   (ws + 25690112);                 //  1,048,576 B
    int*    idx1      = (int*)   (ws + 26738688);                 //  1,048,576 B
    int*    dec       = (int*)   (ws + 27787264);                 //     65,536 B
    float2* respd     = (float2*)(ws + 27852800);                 //    131,072 B
    int*    flaglist  = (int*)   (ws + 27983872);                 //     32,768 B
    unsigned short* awhl = (unsigned short*)(ws + 28016640);      //     32,768 B
    char*   misc      = ws + 28049408;
    int*    cnt0      = (int*)   (misc + 0);
    int*    cnt1      = (int*)   (misc + 64);
    float*  importance= (float*) (misc + 128);
    int*    nflag     = (int*)   (misc + 192);
    int*    wflag     = (int*)   (misc + 196);
    int*    sn0       = (int*)   (misc + 200);
    int*    sn1       = (int*)   (misc + 204);
    int*    sched0    = (int*)   (misc + 256);
    int*    sched1    = (int*)   (misc + 896);

    k_prep<<<1, 256, 0, stream>>>(assign_w, awhl, cnt0, cnt1, importance, nflag, wflag);
    k_wconv<<<(NE_TOT * OUTD * CDIM / 4 + 255) / 256, 256, 0, stream>>>(pw_w1, bias_w, wbf, wflag);
    k_gate<<<TB / 64, 256, 0, stream>>>(x, awhl, assign_b, xbf, dec, respd,
                                        flaglist, nflag, importance);
    k_repair<<<32, 256, 0, stream>>>(x, assign_w, assign_b, flaglist, nflag,
                                     dec, respd, importance);
    k_build<<<TB / 256, 256, 0, stream>>>(dec, cnt0, cnt1, idx0, idx1);
    k_finish<<<1, 128, 0, stream>>>(importance, loss, cnt0, cnt1, sched0, sched1, sn0, sn1);
    k_gemm<0><<<dim3(OUTD / BN, MAX_SCHED), 256, 0, stream>>>(
        xbf, wbf, cnt0, idx0, respd, sched0, sn0, bias_b, y);
    k_gemm<1><<<dim3(OUTD / BN, MAX_SCHED), 256, 0, stream>>>(
        xbf, wbf, cnt1, idx1, respd, sched1, sn1, bias_b, y);
    k_dense<<<dim3(OUTD / BN, TB / BM), 256, 0, stream>>>(xbf, wbf, wflag, y);
}